// Round 11
// baseline (5022.952 us; speedup 1.0000x reference)
//
#include <hip/hip_runtime.h>
#include <cstdint>
#include <cstddef>

#define B_SZ   4
#define N_PTS  16384
#define M_CENT 2048
#define NSAMP  32
#define C_IN   64
#define H1_DIM 64
#define H2_DIM 128
#define FPS_T  1024
#define NCELL  512                // 8x8x8 cells; EACH CELL IS A PRUNING UNIT
#define CKI(c) ((c) + ((c) >> 4)) // pad per-cell arrays (stride-17 dwords)
#define NCLP   (NCELL + (NCELL >> 4)) // 544 padded entries
#define H0_STR 68                 // 67 channels padded to 68 for 16B-aligned float4

// u64 max with neighbor fetched via DPP (invalid lanes keep self = identity
// under max). HW-verified rounds 3-10.
template <int CTRL>
__device__ __forceinline__ unsigned long long kmax_dpp(unsigned long long k) {
  const int lo  = (int)(unsigned)(k & 0xFFFFFFFFULL);
  const int hi  = (int)(unsigned)(k >> 32);
  const int olo = __builtin_amdgcn_update_dpp(lo, lo, CTRL, 0xF, 0xF, false);
  const int ohi = __builtin_amdgcn_update_dpp(hi, hi, CTRL, 0xF, 0xF, false);
  const unsigned long long o =
      ((unsigned long long)(unsigned)ohi << 32) | (unsigned)olo;
  return (o > k) ? o : k;
}

// Spread 3-bit value v to bits 0,3,6 (Morton part).
__device__ __forceinline__ int mpart(int v) {
  return (v & 1) | ((v & 2) << 2) | ((v & 4) << 4);
}

// ---------------------------------------------------------------------------
// K1: EXACT spatially-pruned FPS, v3 (cell-clusters). One 1024-thr block/batch.
// r10 post-mortem: F~128/256 fixed 64-pt clusters updated per iter. Root
// cause is OCCUPANCY SKEW, not curve order: 26% of Gaussian points lie at
// r>2sigma where cells hold 1-5 pts, so 64-pt chunks span dozens of cells ->
// rad 1.5-3sigma -> gap<0 forever -> ~70+ permanently-flagged clusters.
// Fix: the pruning unit IS the cell (512 cells, variable cnt, avg 32).
// Members lie inside a ~0.9sigma box -> rad <= 0.78sigma REGARDLESS of
// occupancy; sphere still built from actual members (tighter for sparse).
// Phase A: 32 cells/wave (lane<32, c=lane*16+wave). Phase B: flagged cells,
// for(j=lane;j<cnt;j+=64) over slot range; exact u64 key rebuild via 6-lvl
// DPP. Phase C: 512 exact keys -> own-slice DPP reduce (r9/r10-proven).
// Empty cells: ckey=0 (never argmax), rad=0 (always skipped). Correctness
// unchanged vs r9/r10 (both PASSED): skip only when (dq-rad)^2 > ub*1.001+
// 1e-5 with inflated rad -> skipped mins provable identities -> pd and the
// u64 (dist, N-origidx) argmax bit-exact (max dist, min orig idx on tie).
// Cell membership/spheres deterministic; atomic scatter order only permutes
// slots within a cell (keys use orig indices -> outputs unchanged).
// ---------------------------------------------------------------------------
__global__ __launch_bounds__(FPS_T, 4) void fps_kernel(const float* __restrict__ xyz,
                                                       float* __restrict__ out_xyz) {
#pragma clang fp contract(off)
  const int b    = blockIdx.x;
  const int t    = threadIdx.x;
  const int lane = t & 63;
  const int wave = t >> 6;           // 16 waves
  const float* bx = xyz + (size_t)b * N_PTS * 3;
  float* ox = out_xyz + (size_t)b * M_CENT * 3;

  __shared__ float              pd_l[N_PTS];       // 64K  running min-dist^2 (by slot)
  __shared__ unsigned short     sidx[N_PTS];       // 32K  slot -> orig idx
  __shared__ float              ccx[NCLP];         // padded cell sphere centers
  __shared__ float              ccy[NCLP];
  __shared__ float              ccz[NCLP];
  __shared__ float              crad_[NCLP];       // inflated radii
  __shared__ unsigned long long ckey[NCLP];        // exact cell keys (4.3K)
  __shared__ int                hist[NCELL];       // cell counts
  __shared__ int                offs[NCELL];       // scatter cursors
  __shared__ int                cstart[NCELL];     // cell start slots
  __shared__ unsigned long long s_key[2][16];
  __shared__ float              s_part[16][6];
  __shared__ float              s_bbox[6];

  // ---- preprocess 1: bounding box ----
  {
    float mnx = 1e30f, mny = 1e30f, mnz = 1e30f;
    float mxx = -1e30f, mxy = -1e30f, mxz = -1e30f;
    for (int i = t; i < N_PTS; i += FPS_T) {
      const float x = bx[i * 3 + 0], y = bx[i * 3 + 1], z = bx[i * 3 + 2];
      mnx = fminf(mnx, x); mxx = fmaxf(mxx, x);
      mny = fminf(mny, y); mxy = fmaxf(mxy, y);
      mnz = fminf(mnz, z); mxz = fmaxf(mxz, z);
    }
    for (int off = 32; off >= 1; off >>= 1) {
      mnx = fminf(mnx, __shfl_xor(mnx, off)); mxx = fmaxf(mxx, __shfl_xor(mxx, off));
      mny = fminf(mny, __shfl_xor(mny, off)); mxy = fmaxf(mxy, __shfl_xor(mxy, off));
      mnz = fminf(mnz, __shfl_xor(mnz, off)); mxz = fmaxf(mxz, __shfl_xor(mxz, off));
    }
    if (lane == 0) {
      s_part[wave][0] = mnx; s_part[wave][1] = mny; s_part[wave][2] = mnz;
      s_part[wave][3] = mxx; s_part[wave][4] = mxy; s_part[wave][5] = mxz;
    }
    __syncthreads();
    if (t == 0) {
      float v0 = 1e30f, v1 = 1e30f, v2 = 1e30f, v3 = -1e30f, v4 = -1e30f, v5 = -1e30f;
      for (int w = 0; w < 16; ++w) {
        v0 = fminf(v0, s_part[w][0]); v1 = fminf(v1, s_part[w][1]);
        v2 = fminf(v2, s_part[w][2]); v3 = fmaxf(v3, s_part[w][3]);
        v4 = fmaxf(v4, s_part[w][4]); v5 = fmaxf(v5, s_part[w][5]);
      }
      s_bbox[0] = v0; s_bbox[1] = v1; s_bbox[2] = v2;
      s_bbox[3] = 8.0f / fmaxf(v3 - v0, 1e-20f);   // inv widths
      s_bbox[4] = 8.0f / fmaxf(v4 - v1, 1e-20f);
      s_bbox[5] = 8.0f / fmaxf(v5 - v2, 1e-20f);
    }
    if (t < NCELL) hist[t] = 0;
    __syncthreads();
  }
  const float bb0 = s_bbox[0], bb1 = s_bbox[1], bb2 = s_bbox[2];
  const float iw0 = s_bbox[3], iw1 = s_bbox[4], iw2 = s_bbox[5];

  // ---- preprocess 2: histogram, prefix(+cstart), scatter (Morton cells) ----
  for (int i = t; i < N_PTS; i += FPS_T) {
    const float x = bx[i * 3 + 0], y = bx[i * 3 + 1], z = bx[i * 3 + 2];
    int qx = (int)((x - bb0) * iw0); qx = qx > 7 ? 7 : qx;
    int qy = (int)((y - bb1) * iw1); qy = qy > 7 ? 7 : qy;
    int qz = (int)((z - bb2) * iw2); qz = qz > 7 ? 7 : qz;
    atomicAdd(&hist[(mpart(qx) << 2) | (mpart(qy) << 1) | mpart(qz)], 1);
  }
  __syncthreads();
  if (t < NCELL) {
    int s = 0;
    for (int i = 0; i < t; ++i) s += hist[i];
    offs[t]   = s;
    cstart[t] = s;
  }
  __syncthreads();
  for (int i = t; i < N_PTS; i += FPS_T) {
    const float x = bx[i * 3 + 0], y = bx[i * 3 + 1], z = bx[i * 3 + 2];
    int qx = (int)((x - bb0) * iw0); qx = qx > 7 ? 7 : qx;
    int qy = (int)((y - bb1) * iw1); qy = qy > 7 ? 7 : qy;
    int qz = (int)((z - bb2) * iw2); qz = qz > 7 ? 7 : qz;
    const int slot = atomicAdd(&offs[(mpart(qx) << 2) | (mpart(qy) << 1) | mpart(qz)], 1);
    sidx[slot] = (unsigned short)i;
  }
  for (int i = t; i < N_PTS; i += FPS_T) pd_l[i] = 1e10f;  // BIG
  __syncthreads();

  // ---- preprocess 3: per-cell bounding spheres from members (2 passes) ----
  for (int c = wave; c < NCELL; c += 16) {
    const int st = cstart[c], cn = hist[c];
    const int ci = CKI(c);
    if (cn == 0) {
      if (lane == 0) { ccx[ci] = 0.f; ccy[ci] = 0.f; ccz[ci] = 0.f; crad_[ci] = 0.f; ckey[ci] = 0ULL; }
      continue;
    }
    float mnx = 1e30f, mxx = -1e30f, mny = 1e30f, mxy = -1e30f, mnz = 1e30f, mxz = -1e30f;
    for (int j = lane; j < cn; j += 64) {
      const int oi = (int)sidx[st + j];
      const float x = bx[oi * 3 + 0], y = bx[oi * 3 + 1], z = bx[oi * 3 + 2];
      mnx = fminf(mnx, x); mxx = fmaxf(mxx, x);
      mny = fminf(mny, y); mxy = fmaxf(mxy, y);
      mnz = fminf(mnz, z); mxz = fmaxf(mxz, z);
    }
    for (int off = 32; off >= 1; off >>= 1) {
      mnx = fminf(mnx, __shfl_xor(mnx, off)); mxx = fmaxf(mxx, __shfl_xor(mxx, off));
      mny = fminf(mny, __shfl_xor(mny, off)); mxy = fmaxf(mxy, __shfl_xor(mxy, off));
      mnz = fminf(mnz, __shfl_xor(mnz, off)); mxz = fmaxf(mxz, __shfl_xor(mxz, off));
    }
    const float ctx = (mnx + mxx) * 0.5f, cty = (mny + mxy) * 0.5f, ctz = (mnz + mxz) * 0.5f;
    float dd = 0.0f;
    for (int j = lane; j < cn; j += 64) {
      const int oi = (int)sidx[st + j];
      const float ddx = bx[oi * 3 + 0] - ctx;
      const float ddy = bx[oi * 3 + 1] - cty;
      const float ddz = bx[oi * 3 + 2] - ctz;
      dd = fmaxf(dd, sqrtf(ddx * ddx + ddy * ddy + ddz * ddz));
    }
    for (int off = 32; off >= 1; off >>= 1) dd = fmaxf(dd, __shfl_xor(dd, off));
    if (lane == 0) {
      ccx[ci] = ctx; ccy[ci] = cty; ccz[ci] = ctz;
      crad_[ci] = dd * 1.0002f + 1e-6f;                  // conservative inflation
      ckey[ci]  = 0x501502F900000001ULL;                 // (bits(1e10)<<32)|1
    }
  }
  __syncthreads();

  // ---- main loop ----
  int cur = 0;  // reference idx0 = 0 (original index)
  for (int m = 0; m < M_CENT; ++m) {
    const int curs = __builtin_amdgcn_readfirstlane(cur);
    const float cx = bx[curs * 3 + 0];
    const float cy = bx[curs * 3 + 1];
    const float cz = bx[curs * 3 + 2];
    if (t == 0) { ox[m * 3 + 0] = cx; ox[m * 3 + 1] = cy; ox[m * 3 + 2] = cz; }
    if (m == M_CENT - 1) break;

    // Phase A: skip test, 32 cells per wave (lane<32): c = lane*16 + wave.
    // Own-slice (ckey[c] written only by this wave) -> race-free.
    bool upd = false;
    if (lane < 32) {
      const int ci = CKI(lane * 16 + wave);
      const float qx = ccx[ci] - cx;
      const float qy = ccy[ci] - cy;
      const float qz = ccz[ci] - cz;
      const float dq  = sqrtf(qx * qx + qy * qy + qz * qz);
      const float gap = dq - crad_[ci];
      const float ub  = __uint_as_float((unsigned)(ckey[ci] >> 32));
      upd = !((gap > 0.0f) && (gap * gap > ub * 1.001f + 1e-5f));
    }
    unsigned long long mask = __ballot(upd);

    // Phase B: update flagged cells (whole wave per cell, variable cnt)
    while (mask) {
      const int s = __builtin_ctzll(mask);
      mask &= mask - 1;
      const int c  = s * 16 + wave;
      const int st = cstart[c];
      const int cn = hist[c];
      unsigned long long key = 0ULL;
      for (int j = lane; j < cn; j += 64) {
        const int slot = st + j;
        const int oi   = (int)sidx[slot];
        const float x = bx[oi * 3 + 0], y = bx[oi * 3 + 1], z = bx[oi * 3 + 2];
        const float dx = x - cx, dy = y - cy, dz = z - cz;
        const float d2 = (dx * dx + dy * dy) + dz * dz;   // numpy order, no FMA
        const float nd = fminf(pd_l[slot], d2);
        pd_l[slot] = nd;
        const unsigned long long k = ((unsigned long long)__float_as_uint(nd) << 32)
                                   | (unsigned int)(N_PTS - oi);
        key = (k > key) ? k : key;
      }
      key = kmax_dpp<0x111>(key);
      key = kmax_dpp<0x112>(key);
      key = kmax_dpp<0x114>(key);
      key = kmax_dpp<0x118>(key);
      key = kmax_dpp<0x142>(key);
      key = kmax_dpp<0x143>(key);
      if (lane == 63) ckey[CKI(c)] = key;
    }

    // Phase C: global argmax over 512 exact cell keys (own-slice reduce).
    unsigned long long wk = (lane < 32) ? ckey[CKI(lane * 16 + wave)] : 0ULL;
    wk = kmax_dpp<0x111>(wk);
    wk = kmax_dpp<0x112>(wk);
    wk = kmax_dpp<0x114>(wk);
    wk = kmax_dpp<0x118>(wk);
    wk = kmax_dpp<0x142>(wk);
    wk = kmax_dpp<0x143>(wk);
    const int p = m & 1;
    if (lane == 63) s_key[p][wave] = wk;
    __syncthreads();
    unsigned long long k2 = s_key[p][lane & 15];
    k2 = kmax_dpp<0x111>(k2);
    k2 = kmax_dpp<0x112>(k2);
    k2 = kmax_dpp<0x114>(k2);
    k2 = kmax_dpp<0x118>(k2);
    const int lo15 = __builtin_amdgcn_readlane((int)(unsigned)(k2 & 0xFFFFFFFFULL), 15);
    cur = N_PTS - lo15;
  }
}

// ---------------------------------------------------------------------------
// K2: Ball query. One wave per centroid: ballot + prefix popcount appends the
// first 32 in-radius indices in index order (== top_k(-order) semantics),
// pads with the first hit. Early exit once 32 found.
// ---------------------------------------------------------------------------
__global__ __launch_bounds__(256) void ballq_kernel(const float* __restrict__ xyz,
                                                    const float* __restrict__ new_xyz,
                                                    int* __restrict__ idx_out) {
#pragma clang fp contract(off)
  const int lane = threadIdx.x & 63;
  const int gid  = blockIdx.x * 4 + (threadIdx.x >> 6);
  if (gid >= B_SZ * M_CENT) return;
  const int b = gid >> 11;  // / M_CENT
  const float* bx = xyz + (size_t)b * N_PTS * 3;
  const float cx = new_xyz[gid * 3 + 0];
  const float cy = new_xyz[gid * 3 + 1];
  const float cz = new_xyz[gid * 3 + 2];
  const float rr = (float)(0.8 * 0.8);  // double 0.64 -> f32 (JAX weak-scalar cast)
  int* out = idx_out + (size_t)gid * NSAMP;

  int count = 0;
  int first = -1;
  for (int base = 0; base < N_PTS; base += 64) {
    const int i = base + lane;
    const float dx = bx[i * 3 + 0] - cx;
    const float dy = bx[i * 3 + 1] - cy;
    const float dz = bx[i * 3 + 2] - cz;
    const float d = (dx * dx + dy * dy) + dz * dz;
    const bool pred = d < rr;
    const unsigned long long mk = __ballot(pred);
    if (pred) {
      const int slot = count + __popcll(mk & ((1ULL << lane) - 1ULL));
      if (slot < NSAMP) out[slot] = i;
    }
    if (first < 0 && mk != 0ULL) first = base + (__ffsll((long long)mk) - 1);
    count += __popcll(mk);
    if (count >= NSAMP) break;
  }
  if (count < NSAMP) {
    for (int k = count + lane; k < NSAMP; k += 64) out[k] = first;  // centroid itself is a hit
  }
}

// ---------------------------------------------------------------------------
// K3: gather + MLP(67->64 relu, 64->128 relu) + max over 32 samples.
// One 128-thread block per centroid. h0/h1 staged in LDS; reads are
// wave-uniform float4 broadcasts; weights coalesced from L1/L2.
// ---------------------------------------------------------------------------
__global__ __launch_bounds__(128) void mlp_kernel(const float* __restrict__ xyz,
                                                  const float* __restrict__ feats,
                                                  const float* __restrict__ new_xyz,
                                                  const int* __restrict__ idx,
                                                  const float* __restrict__ w1,
                                                  const float* __restrict__ b1,
                                                  const float* __restrict__ w2,
                                                  const float* __restrict__ b2,
                                                  float* __restrict__ out_feats) {
  const int gid = blockIdx.x;
  const int t   = threadIdx.x;
  const int b   = gid >> 11;  // / M_CENT

  __shared__ float h0[NSAMP * H0_STR];
  __shared__ float h1[NSAMP * H1_DIM];
  __shared__ int   sidx[NSAMP];

  if (t < NSAMP) sidx[t] = idx[(size_t)gid * NSAMP + t];
  const float cx = new_xyz[gid * 3 + 0];
  const float cy = new_xyz[gid * 3 + 1];
  const float cz = new_xyz[gid * 3 + 2];
  __syncthreads();

  const float* bxyz = xyz + (size_t)b * N_PTS * 3;
  const float* bft  = feats + (size_t)b * N_PTS * C_IN;
  for (int e = t; e < NSAMP * 67; e += 128) {
    const int s = e / 67;
    const int c = e - s * 67;
    const int p = sidx[s];
    float v;
    if (c < 3) {
      const float pc = bxyz[p * 3 + c];
      v = pc - (c == 0 ? cx : (c == 1 ? cy : cz));
    } else {
      v = bft[(size_t)p * C_IN + (c - 3)];
    }
    h0[s * H0_STR + c] = v;
  }
  __syncthreads();

  // layer 1: col = t&63 over H1_DIM, half = t>>6 picks 16 of 32 samples
  {
    const int col  = t & 63;
    const int half = t >> 6;
    float acc[16];
    const float bb = b1[col];
#pragma unroll
    for (int s = 0; s < 16; ++s) acc[s] = bb;
    const float* h0base = h0 + (half * 16) * H0_STR;
    for (int k = 0; k < 64; k += 4) {
      const float w0v = w1[(k + 0) * H1_DIM + col];
      const float w1v = w1[(k + 1) * H1_DIM + col];
      const float w2v = w1[(k + 2) * H1_DIM + col];
      const float w3v = w1[(k + 3) * H1_DIM + col];
#pragma unroll
      for (int s = 0; s < 16; ++s) {
        const float4 h4 = *reinterpret_cast<const float4*>(h0base + s * H0_STR + k);
        acc[s] += h4.x * w0v + h4.y * w1v + h4.z * w2v + h4.w * w3v;
      }
    }
    for (int k = 64; k < 67; ++k) {
      const float wv = w1[k * H1_DIM + col];
#pragma unroll
      for (int s = 0; s < 16; ++s) acc[s] += h0base[s * H0_STR + k] * wv;
    }
#pragma unroll
    for (int s = 0; s < 16; ++s) h1[(half * 16 + s) * H1_DIM + col] = fmaxf(acc[s], 0.0f);
  }
  __syncthreads();

  // layer 2 + max-pool: col = t over H2_DIM
  {
    float acc[32];
    const float bb = b2[t];
#pragma unroll
    for (int s = 0; s < 32; ++s) acc[s] = bb;
    for (int k = 0; k < 64; k += 4) {
      const float w0v = w2[(k + 0) * H2_DIM + t];
      const float w1v = w2[(k + 1) * H2_DIM + t];
      const float w2v = w2[(k + 2) * H2_DIM + t];
      const float w3v = w2[(k + 3) * H2_DIM + t];
#pragma unroll
      for (int s = 0; s < 32; ++s) {
        const float4 h4 = *reinterpret_cast<const float4*>(&h1[s * H1_DIM + k]);
        acc[s] += h4.x * w0v + h4.y * w1v + h4.z * w2v + h4.w * w3v;
      }
    }
    float mx = 0.0f;  // max(relu(v)) == max(0, max(v))
#pragma unroll
    for (int s = 0; s < 32; ++s) mx = fmaxf(mx, acc[s]);
    out_feats[(size_t)gid * H2_DIM + t] = mx;
  }
}

// ---------------------------------------------------------------------------
extern "C" void kernel_launch(void* const* d_in, const int* in_sizes, int n_in,
                              void* d_out, int out_size, void* d_ws, size_t ws_size,
                              hipStream_t stream) {
  const float* xyz   = (const float*)d_in[0];  // (4,16384,3) f32
  const float* feats = (const float*)d_in[1];  // (4,16384,64) f32
  // d_in[2] = bid (unused; output bid is all zeros)
  const float* w1 = (const float*)d_in[3];     // (67,64)
  const float* b1 = (const float*)d_in[4];     // (64,)
  const float* w2 = (const float*)d_in[5];     // (64,128)
  const float* b2 = (const float*)d_in[6];     // (128,)

  float* out       = (float*)d_out;
  float* out_xyz   = out;                                        // (4,2048,3)
  float* out_feats = out + (size_t)B_SZ * M_CENT * 3;            // (4,2048,128)
  float* out_bid   = out_feats + (size_t)B_SZ * M_CENT * H2_DIM; // (4,2048,1) int32 zeros
  int*   idx_ws    = (int*)d_ws;                                 // (4,2048,32) int32, 1 MiB

  hipLaunchKernelGGL(fps_kernel, dim3(B_SZ), dim3(FPS_T), 0, stream, xyz, out_xyz);
  hipLaunchKernelGGL(ballq_kernel, dim3((B_SZ * M_CENT + 3) / 4), dim3(256), 0, stream,
                     xyz, out_xyz, idx_ws);
  hipLaunchKernelGGL(mlp_kernel, dim3(B_SZ * M_CENT), dim3(128), 0, stream,
                     xyz, feats, out_xyz, idx_ws, w1, b1, w2, b2, out_feats);
  hipMemsetAsync(out_bid, 0, (size_t)B_SZ * M_CENT * sizeof(int), stream);
}

// Round 12
// 3431.391 us; speedup vs baseline: 1.4638x; 1.4638x over previous
//
#include <hip/hip_runtime.h>
#include <cstdint>
#include <cstddef>

#define B_SZ   4
#define N_PTS  16384
#define M_CENT 2048
#define NSAMP  32
#define C_IN   64
#define H1_DIM 64
#define H2_DIM 128
#define BLK_T  512
#define PPT    (N_PTS / BLK_T)    // 32 points per thread (producer)
#define PAIRS  (PPT / 2)          // 16 SoA float2 pairs per thread
#define NBLK   256                // 4 producer + 252 consumer blocks
#define TASK_WAVES ((NBLK - 4) * 2)
#define PUB_STEP 16               // producer publishes progress every 16 iters

typedef float v2f __attribute__((ext_vector_type(2)));

// u64 max with neighbor fetched via DPP (invalid lanes keep self = identity
// under max). HW-verified rounds 3-11.
template <int CTRL>
__device__ __forceinline__ unsigned long long kmax_dpp(unsigned long long k) {
  const int lo  = (int)(unsigned)(k & 0xFFFFFFFFULL);
  const int hi  = (int)(unsigned)(k >> 32);
  const int olo = __builtin_amdgcn_update_dpp(lo, lo, CTRL, 0xF, 0xF, false);
  const int ohi = __builtin_amdgcn_update_dpp(hi, hi, CTRL, 0xF, 0xF, false);
  const unsigned long long o =
      ((unsigned long long)(unsigned)ohi << 32) | (unsigned)olo;
  return (o > k) ? o : k;
}

// Wave-local LDS fence: this wave's ds writes are visible to its own later
// reads of OTHER lanes' addresses (compiler can't see cross-lane deps).
// "memory" clobber orders the surrounding loads/stores; sched_barrier pins.
__device__ __forceinline__ void wave_lds_fence() {
  asm volatile("s_waitcnt lgkmcnt(0)" ::: "memory");
  __builtin_amdgcn_sched_barrier(0);
}

// ---------------------------------------------------------------------------
// Fused kernel. Blocks 0-3: the r4 brute-force FPS VERBATIM (best measured,
// 3257 us; pruning r9-r11 all lost to its zero-divergence loop) + batched
// progress publication. Blocks 4-255: persistent consumers -- 2 task-waves
// each (waves 2-7 exit; no __syncthreads on the consumer path), each wave
// grabs task tau = (b = tau&3, m = tau>>2), polls prog[b] (relaxed + s_sleep,
// one acquire on success), then runs ballq + MLP for that centroid with
// op-order identical to the r4 kernels (idx held in per-wave LDS).
// Deadlock-impossible: 256 blocks / 1072 waves / <=35 KB LDS all co-resident;
// consumers wait only on producers; producers never wait.
// ---------------------------------------------------------------------------
__global__ __launch_bounds__(BLK_T, 1) void fused_kernel(
    const float* __restrict__ xyz, const float* __restrict__ feats,
    const float* __restrict__ w1, const float* __restrict__ b1,
    const float* __restrict__ w2, const float* __restrict__ b2,
    float* __restrict__ out_xyz, float* __restrict__ out_feats,
    int* __restrict__ prog) {
#pragma clang fp contract(off)
  __shared__ unsigned long long s_key[2][8];        // producer reduce slots
  __shared__ float s_h0[2][NSAMP * 68];             // consumer: per-wave h0 (68-pad)
  __shared__ float s_h1[2][NSAMP * H1_DIM];         // consumer: per-wave h1
  __shared__ int   s_widx[2][NSAMP];                // consumer: ball-query idx

  const int t    = threadIdx.x;
  const int lane = t & 63;
  const int wave = t >> 6;

  if (blockIdx.x < B_SZ) {
    // =================== PRODUCER: r4 FPS, verbatim + prog ===================
    const int b = blockIdx.x;
    const float* bx = xyz + (size_t)b * N_PTS * 3;
    float* ox = out_xyz + (size_t)b * M_CENT * 3;

    v2f px[PAIRS], py[PAIRS], pz[PAIRS], pdp[PAIRS];
#pragma unroll
    for (int k = 0; k < PAIRS; ++k) {
      const int i0 = (2 * k + 0) * BLK_T + t;
      const int i1 = (2 * k + 1) * BLK_T + t;
      v2f vx, vy, vz;
      vx.x = bx[i0 * 3 + 0]; vx.y = bx[i1 * 3 + 0];
      vy.x = bx[i0 * 3 + 1]; vy.y = bx[i1 * 3 + 1];
      vz.x = bx[i0 * 3 + 2]; vz.y = bx[i1 * 3 + 2];
      px[k] = vx; py[k] = vy; pz[k] = vz;
      v2f big; big.x = 1e10f; big.y = 1e10f;  // BIG
      pdp[k] = big;
    }
    // Init-only pin: loads cannot be re-materialized inside the m-loop (r2).
    asm volatile("" : "+v"(px[0]), "+v"(px[1]), "+v"(px[2]),  "+v"(px[3]),
                      "+v"(px[4]), "+v"(px[5]), "+v"(px[6]),  "+v"(px[7]),
                      "+v"(px[8]), "+v"(px[9]), "+v"(px[10]), "+v"(px[11]),
                      "+v"(px[12]),"+v"(px[13]),"+v"(px[14]), "+v"(px[15]));
    asm volatile("" : "+v"(py[0]), "+v"(py[1]), "+v"(py[2]),  "+v"(py[3]),
                      "+v"(py[4]), "+v"(py[5]), "+v"(py[6]),  "+v"(py[7]),
                      "+v"(py[8]), "+v"(py[9]), "+v"(py[10]), "+v"(py[11]),
                      "+v"(py[12]),"+v"(py[13]),"+v"(py[14]), "+v"(py[15]));
    asm volatile("" : "+v"(pz[0]), "+v"(pz[1]), "+v"(pz[2]),  "+v"(pz[3]),
                      "+v"(pz[4]), "+v"(pz[5]), "+v"(pz[6]),  "+v"(pz[7]),
                      "+v"(pz[8]), "+v"(pz[9]), "+v"(pz[10]), "+v"(pz[11]),
                      "+v"(pz[12]),"+v"(pz[13]),"+v"(pz[14]), "+v"(pz[15]));

    int cur = 0;  // reference idx0 = 0
    for (int m = 0; m < M_CENT; ++m) {
      const int curs = __builtin_amdgcn_readfirstlane(cur);  // uniform
      const float cx = bx[curs * 3 + 0];                     // L2-hot broadcast
      const float cy = bx[curs * 3 + 1];
      const float cz = bx[curs * 3 + 2];
      if (t == 0) {
        ox[m * 3 + 0] = cx; ox[m * 3 + 1] = cy; ox[m * 3 + 2] = cz;
        // Batched release publication: centroids [0, m] now visible.
        // PUB_STEP=16 amortizes the vmcnt-drain release cost (~25 cyc/iter).
        if ((m & (PUB_STEP - 1)) == (PUB_STEP - 1)) {
          __hip_atomic_store(&prog[b], m + 1, __ATOMIC_RELEASE,
                             __HIP_MEMORY_SCOPE_AGENT);
        }
      }
      if (m == M_CENT - 1) break;

      v2f vcx, vcy, vcz;
      vcx.x = cx; vcx.y = cx;
      vcy.x = cy; vcy.y = cy;
      vcz.x = cz; vcz.y = cz;
      float bv = -1.0f;  // dists >= 0, so first point always taken
      int   bi = 0;
#pragma unroll
      for (int k = 0; k < PAIRS; ++k) {
        const v2f dx = px[k] - vcx;         // exact per element
        const v2f dy = py[k] - vcy;
        const v2f dz = pz[k] - vcz;
        const v2f sxq = dx * dx;
        const v2f syq = dy * dy;
        const v2f szq = dz * dz;
        const v2f s1  = sxq + syq;
        const v2f d2  = s1 + szq;           // (dx2+dy2)+dz2, numpy order, no FMA
        v2f nd = pdp[k];
        nd.x = fminf(nd.x, d2.x);
        nd.y = fminf(nd.y, d2.y);
        pdp[k] = nd;
        const bool c0 = nd.x > bv;          // strict >: min global idx on tie
        bv = c0 ? nd.x : bv;
        bi = c0 ? ((2 * k + 0) * BLK_T + t) : bi;
        const bool c1 = nd.y > bv;
        bv = c1 ? nd.y : bv;
        bi = c1 ? ((2 * k + 1) * BLK_T + t) : bi;
      }
      // pack: high = float bits (>=0, monotone), low = N-idx (ties -> min idx)
      unsigned long long key = ((unsigned long long)__float_as_uint(bv) << 32)
                             | (unsigned int)(N_PTS - bi);
      key = kmax_dpp<0x111>(key);   // row_shr:1
      key = kmax_dpp<0x112>(key);   // row_shr:2
      key = kmax_dpp<0x114>(key);   // row_shr:4
      key = kmax_dpp<0x118>(key);   // row_shr:8
      key = kmax_dpp<0x142>(key);   // row_bcast15
      key = kmax_dpp<0x143>(key);   // row_bcast31
      const int p = m & 1;
      if (lane == 63) s_key[p][wave] = key;
      __syncthreads();
      unsigned long long k2 = s_key[p][lane & 7];
      k2 = kmax_dpp<0x111>(k2);
      k2 = kmax_dpp<0x112>(k2);
      k2 = kmax_dpp<0x114>(k2);
      const int lo7 = __builtin_amdgcn_readlane((int)(unsigned)(k2 & 0xFFFFFFFFULL), 7);
      cur = N_PTS - lo7;
    }
    // Final publication (covers the tail chunk incl. m = M_CENT-1).
    if (t == 0) {
      __hip_atomic_store(&prog[b], M_CENT, __ATOMIC_RELEASE,
                         __HIP_MEMORY_SCOPE_AGENT);
    }
    return;
  }

  // ========================= CONSUMERS =========================
  if (wave >= 2) return;  // 2 task-waves per block; no __syncthreads below
  const int twid = (blockIdx.x - B_SZ) * 2 + wave;   // 0..TASK_WAVES-1
  const float rr = (float)(0.8 * 0.8);  // double 0.64 -> f32 (JAX weak cast)

  float* h0w = s_h0[wave];
  float* h1w = s_h1[wave];
  int*   widx = s_widx[wave];

  for (int tau = twid; tau < B_SZ * M_CENT; tau += TASK_WAVES) {
    const int b = tau & 3;
    const int m = tau >> 2;
    // wait for producer (relaxed poll + sleep; one acquire fence on success)
    while (__hip_atomic_load(&prog[b], __ATOMIC_RELAXED,
                             __HIP_MEMORY_SCOPE_AGENT) <= m) {
      __builtin_amdgcn_s_sleep(32);
    }
    (void)__hip_atomic_load(&prog[b], __ATOMIC_ACQUIRE, __HIP_MEMORY_SCOPE_AGENT);

    const size_t gid = (size_t)b * M_CENT + m;
    const float* bx  = xyz + (size_t)b * N_PTS * 3;
    const float* bft = feats + (size_t)b * N_PTS * C_IN;
    const float cx = out_xyz[gid * 3 + 0];
    const float cy = out_xyz[gid * 3 + 1];
    const float cz = out_xyz[gid * 3 + 2];

    // ---- ball query (identical semantics to the r4 ballq kernel) ----
    {
      int count = 0;
      int first = -1;
      for (int base = 0; base < N_PTS; base += 64) {
        const int i = base + lane;
        const float dx = bx[i * 3 + 0] - cx;
        const float dy = bx[i * 3 + 1] - cy;
        const float dz = bx[i * 3 + 2] - cz;
        const float d = (dx * dx + dy * dy) + dz * dz;
        const bool pred = d < rr;
        const unsigned long long mk = __ballot(pred);
        if (pred) {
          const int slot = count + __popcll(mk & ((1ULL << lane) - 1ULL));
          if (slot < NSAMP) widx[slot] = i;
        }
        if (first < 0 && mk != 0ULL) first = base + (__ffsll((long long)mk) - 1);
        count += __popcll(mk);
        if (count >= NSAMP) break;
      }
      if (count < NSAMP) {
        for (int k = count + lane; k < NSAMP; k += 64) widx[k] = first;
      }
      wave_lds_fence();
    }

    // ---- gather h0 (rel xyz ++ feats), identical per-element math ----
    for (int e = lane; e < NSAMP * 67; e += 64) {
      const int s = e / 67;
      const int c = e - s * 67;
      const int p = widx[s];
      float v;
      if (c < 3) {
        const float pc = bx[p * 3 + c];
        v = pc - (c == 0 ? cx : (c == 1 ? cy : cz));
      } else {
        v = bft[(size_t)p * C_IN + (c - 3)];
      }
      h0w[s * 68 + c] = v;
    }
    wave_lds_fence();

    // ---- layer 1: lane = col over 64, all 32 samples ----
    {
      float acc[NSAMP];
      const float bb = b1[lane];
#pragma unroll
      for (int s = 0; s < NSAMP; ++s) acc[s] = bb;
      for (int k = 0; k < 64; k += 4) {
        const float w0v = w1[(k + 0) * H1_DIM + lane];
        const float w1v = w1[(k + 1) * H1_DIM + lane];
        const float w2v = w1[(k + 2) * H1_DIM + lane];
        const float w3v = w1[(k + 3) * H1_DIM + lane];
#pragma unroll
        for (int s = 0; s < NSAMP; ++s) {
          const float4 h4 = *reinterpret_cast<const float4*>(h0w + s * 68 + k);
          acc[s] += h4.x * w0v + h4.y * w1v + h4.z * w2v + h4.w * w3v;
        }
      }
      for (int k = 64; k < 67; ++k) {
        const float wv = w1[k * H1_DIM + lane];
#pragma unroll
        for (int s = 0; s < NSAMP; ++s) acc[s] += h0w[s * 68 + k] * wv;
      }
#pragma unroll
      for (int s = 0; s < NSAMP; ++s) h1w[s * H1_DIM + lane] = fmaxf(acc[s], 0.0f);
      wave_lds_fence();
    }

    // ---- layer 2 + max-pool: two passes, col = lane + pass*64 ----
    for (int pass = 0; pass < 2; ++pass) {
      const int col = lane + pass * 64;
      float acc[NSAMP];
      const float bb = b2[col];
#pragma unroll
      for (int s = 0; s < NSAMP; ++s) acc[s] = bb;
      for (int k = 0; k < 64; k += 4) {
        const float w0v = w2[(k + 0) * H2_DIM + col];
        const float w1v = w2[(k + 1) * H2_DIM + col];
        const float w2v = w2[(k + 2) * H2_DIM + col];
        const float w3v = w2[(k + 3) * H2_DIM + col];
#pragma unroll
        for (int s = 0; s < NSAMP; ++s) {
          const float4 h4 = *reinterpret_cast<const float4*>(&h1w[s * H1_DIM + k]);
          acc[s] += h4.x * w0v + h4.y * w1v + h4.z * w2v + h4.w * w3v;
        }
      }
      float mx = 0.0f;  // max(relu(v)) == max(0, max(v))
#pragma unroll
      for (int s = 0; s < NSAMP; ++s) mx = fmaxf(mx, acc[s]);
      out_feats[gid * H2_DIM + col] = mx;
    }
    // widx/h0w/h1w reused next task by the SAME wave -- no cross-wave hazard.
  }
}

// ---------------------------------------------------------------------------
extern "C" void kernel_launch(void* const* d_in, const int* in_sizes, int n_in,
                              void* d_out, int out_size, void* d_ws, size_t ws_size,
                              hipStream_t stream) {
  const float* xyz   = (const float*)d_in[0];  // (4,16384,3) f32
  const float* feats = (const float*)d_in[1];  // (4,16384,64) f32
  // d_in[2] = bid (unused; output bid is all zeros)
  const float* w1 = (const float*)d_in[3];     // (67,64)
  const float* b1 = (const float*)d_in[4];     // (64,)
  const float* w2 = (const float*)d_in[5];     // (64,128)
  const float* b2 = (const float*)d_in[6];     // (128,)

  float* out       = (float*)d_out;
  float* out_xyz   = out;                                        // (4,2048,3)
  float* out_feats = out + (size_t)B_SZ * M_CENT * 3;            // (4,2048,128)
  float* out_bid   = out_feats + (size_t)B_SZ * M_CENT * H2_DIM; // (4,2048,1) int32 zeros
  int*   prog      = (int*)d_ws;                                 // 4 ints, progress

  hipMemsetAsync(prog, 0, B_SZ * sizeof(int), stream);           // clean every replay
  hipLaunchKernelGGL(fused_kernel, dim3(NBLK), dim3(BLK_T), 0, stream,
                     xyz, feats, w1, b1, w2, b2, out_xyz, out_feats, prog);
  hipMemsetAsync(out_bid, 0, (size_t)B_SZ * M_CENT * sizeof(int), stream);
}